// Round 10
// baseline (154.642 us; speedup 1.0000x reference)
//
#include <hip/hip_runtime.h>
#include <hip/hip_bf16.h>

// out[bh][m][d] = sum_k x1[bh][m][k] * x2[bh][k][d];  BH=32, S=2048(M,K), D=64(N), fp32.
// HBM-bound on x1 (537 MB, zero reuse). bf16 MFMA 16x16x32, fp32 acc.
//
// R10 = R2 (best, 116.8 us) + ONE change: 4 LDS buffers, stage 2 tiles ahead,
// __syncthreads only on EVEN K-steps (8 barriers instead of 16). Mechanism:
// each __syncthreads drains vmcnt(0) (compiler-enforced), emptying the CU's
// memory pipe; halving drain count halves the refill-ramp overhead.
// Safety: step T writes buf (T+2)&3, reads buf T&3 / (T+1)&3 (disjoint);
// the last read of the written buffer was before the even-step barrier.
// Everything else identical to R2: BM=128, BK=128, 512 thr, per-step staging,
// x2-loads-before-A-loads, register ping-pong A prefetch, XCD swizzle, no nt.

#define S_DIM 2048
#define D_DIM 64
#define BM 128
#define BK 128
#define NT (S_DIM / BK)   // 16 K-steps
#define LDB (BK + 8)      // byte stride 272: 16B-aligned, 2-way bank pattern (free)

typedef __attribute__((ext_vector_type(8))) short short8;
typedef __attribute__((ext_vector_type(4))) short short4v;
typedef __attribute__((ext_vector_type(4))) float f32x4;

__device__ __forceinline__ short f2bf(float x) {
    return __builtin_bit_cast(short, __float2bfloat16(x));
}

__global__ __launch_bounds__(512, 4)
void pv_gemm_kernel(const float* __restrict__ x1,
                    const float* __restrict__ x2,
                    float* __restrict__ out) {
    __shared__ short lds_b[4][D_DIM][LDB];   // 69,632 B -> 2 blocks/CU

    // XCD-aware bijective swizzle (512 % 8 == 0)
    int bid = blockIdx.x;
    int lb  = (bid & 7) * 64 + (bid >> 3);
    int bh   = lb >> 4;
    int mblk = lb & 15;
    int m0   = mblk * BM;

    int tid  = threadIdx.x;
    int lane = tid & 63;
    int w    = tid >> 6;

    // x2 staging coords: thread t loads column d = t&63, k-block t>>6
    int sd  = tid & 63;
    int skb = tid >> 6;
    const float* x2base = x2 + (size_t)bh * S_DIM * D_DIM + sd;

    // A fragment coords (mfma 16x16x32 bf16: row = lane&15, k = (lane>>4)*8 + j)
    int arow = m0 + w * 16 + (lane & 15);
    int kgrp = (lane >> 4) * 8;
    const float* abase = x1 + ((size_t)bh * S_DIM + arow) * S_DIM + kgrp;

    f32x4 acc[4];
#pragma unroll
    for (int i = 0; i < 4; ++i) acc[i] = (f32x4){0.f, 0.f, 0.f, 0.f};

    // ---- prologue: stage x2 tiles 0 and 1 into buffers 0 and 1
    {
        float rs0[16], rs1[16];
#pragma unroll
        for (int i = 0; i < 16; ++i)
            rs0[i] = x2base[(size_t)(skb * 16 + i) * D_DIM];
        const float* p1 = x2base + (size_t)BK * D_DIM;
#pragma unroll
        for (int i = 0; i < 16; ++i)
            rs1[i] = p1[(size_t)(skb * 16 + i) * D_DIM];
#pragma unroll
        for (int j = 0; j < 4; ++j) {
            short4v v;
            v[0] = f2bf(rs0[4 * j + 0]);
            v[1] = f2bf(rs0[4 * j + 1]);
            v[2] = f2bf(rs0[4 * j + 2]);
            v[3] = f2bf(rs0[4 * j + 3]);
            *(short4v*)&lds_b[0][sd][skb * 16 + 4 * j] = v;
        }
#pragma unroll
        for (int j = 0; j < 4; ++j) {
            short4v v;
            v[0] = f2bf(rs1[4 * j + 0]);
            v[1] = f2bf(rs1[4 * j + 1]);
            v[2] = f2bf(rs1[4 * j + 2]);
            v[3] = f2bf(rs1[4 * j + 3]);
            *(short4v*)&lds_b[1][sd][skb * 16 + 4 * j] = v;
        }
    }

    // ---- prologue: load A tile 0 into rA0
    f32x4 rA0[8], rA1[8];
#pragma unroll
    for (int kk = 0; kk < 4; ++kk) {
        rA0[2 * kk]     = *(const f32x4*)(abase + kk * 32);
        rA0[2 * kk + 1] = *(const f32x4*)(abase + kk * 32 + 4);
    }

// One K-step. BR: LDS buffer to read (== T&3). BW: buffer to write tile T+2
// (== (T+2)&3). Barrier only when DOBAR (even T). x2(T+2) loads issue FIRST,
// A(T+1) second (stays younger in vmcnt FIFO), then MFMA, then ds_write.
#define STEP(T, BR, BW, RA_CUR, RA_NXT, DOBAR)                               \
    {                                                                        \
        if (DOBAR) __syncthreads();                                          \
        float rn[16];                                                        \
        if ((T) + 2 < NT) {                                                  \
            const float* p = x2base + (size_t)((T) + 2) * BK * D_DIM;        \
            _Pragma("unroll")                                                \
            for (int i = 0; i < 16; ++i)                                     \
                rn[i] = p[(size_t)(skb * 16 + i) * D_DIM];                   \
        }                                                                    \
        if ((T) + 1 < NT) {                                                  \
            const float* an = abase + (size_t)((T) + 1) * BK;                \
            _Pragma("unroll")                                                \
            for (int kk = 0; kk < 4; ++kk) {                                 \
                RA_NXT[2 * kk]     = *(const f32x4*)(an + kk * 32);          \
                RA_NXT[2 * kk + 1] = *(const f32x4*)(an + kk * 32 + 4);      \
            }                                                                \
        }                                                                    \
        _Pragma("unroll")                                                    \
        for (int kk = 0; kk < 4; ++kk) {                                     \
            short8 a;                                                        \
            a[0] = f2bf(RA_CUR[2 * kk][0]);                                  \
            a[1] = f2bf(RA_CUR[2 * kk][1]);                                  \
            a[2] = f2bf(RA_CUR[2 * kk][2]);                                  \
            a[3] = f2bf(RA_CUR[2 * kk][3]);                                  \
            a[4] = f2bf(RA_CUR[2 * kk + 1][0]);                              \
            a[5] = f2bf(RA_CUR[2 * kk + 1][1]);                              \
            a[6] = f2bf(RA_CUR[2 * kk + 1][2]);                              \
            a[7] = f2bf(RA_CUR[2 * kk + 1][3]);                              \
            _Pragma("unroll")                                                \
            for (int ni = 0; ni < 4; ++ni) {                                 \
                const short8* bp = (const short8*)                           \
                    &lds_b[BR][ni * 16 + (lane & 15)][kk * 32 + kgrp];       \
                acc[ni] = __builtin_amdgcn_mfma_f32_16x16x32_bf16(           \
                    a, *bp, acc[ni], 0, 0, 0);                               \
            }                                                                \
        }                                                                    \
        if ((T) + 2 < NT) {                                                  \
            _Pragma("unroll")                                                \
            for (int j = 0; j < 4; ++j) {                                    \
                short4v v;                                                   \
                v[0] = f2bf(rn[4 * j + 0]);                                  \
                v[1] = f2bf(rn[4 * j + 1]);                                  \
                v[2] = f2bf(rn[4 * j + 2]);                                  \
                v[3] = f2bf(rn[4 * j + 3]);                                  \
                *(short4v*)&lds_b[BW][sd][skb * 16 + 4 * j] = v;             \
            }                                                                \
        }                                                                    \
    }

    // 16 steps, buffers cycle t&3; barrier on even steps only (8 total).
    STEP(0,  0, 2, rA0, rA1, true)
    STEP(1,  1, 3, rA1, rA0, false)
    STEP(2,  2, 0, rA0, rA1, true)
    STEP(3,  3, 1, rA1, rA0, false)
    STEP(4,  0, 2, rA0, rA1, true)
    STEP(5,  1, 3, rA1, rA0, false)
    STEP(6,  2, 0, rA0, rA1, true)
    STEP(7,  3, 1, rA1, rA0, false)
    STEP(8,  0, 2, rA0, rA1, true)
    STEP(9,  1, 3, rA1, rA0, false)
    STEP(10, 2, 0, rA0, rA1, true)
    STEP(11, 3, 1, rA1, rA0, false)
    STEP(12, 0, 2, rA0, rA1, true)
    STEP(13, 1, 3, rA1, rA0, false)
    STEP(14, 2, 0, rA0, rA1, true)
    STEP(15, 3, 1, rA1, rA0, false)
#undef STEP

    // ---- epilogue: C/D layout col = lane&15, row = (lane>>4)*4 + reg
    int col0 = lane & 15;
    int r0   = m0 + w * 16 + ((lane >> 4) << 2);
    float* ob = out + ((size_t)bh * S_DIM + r0) * D_DIM + col0;
#pragma unroll
    for (int ni = 0; ni < 4; ++ni) {
#pragma unroll
        for (int r = 0; r < 4; ++r)
            ob[(size_t)r * D_DIM + ni * 16] = acc[ni][r];
    }
}

extern "C" void kernel_launch(void* const* d_in, const int* in_sizes, int n_in,
                              void* d_out, int out_size, void* d_ws, size_t ws_size,
                              hipStream_t stream) {
    const float* x1 = (const float*)d_in[0];   // [2,16,2048,2048] softmax probs
    const float* x2 = (const float*)d_in[1];   // [2,16,2048,64]
    float* out = (float*)d_out;                // [2,16,2048,64]

    dim3 grid(512);   // 32 bh * 16 M-tiles
    dim3 block(512);  // 8 waves
    hipLaunchKernelGGL(pv_gemm_kernel, grid, block, 0, stream, x1, x2, out);
}